// Round 9
// baseline (318.377 us; speedup 1.0000x reference)
//
#include <hip/hip_runtime.h>

#define NATOMS 2048
#define R_DIM 512
#define P_DIM 256
#define S_DIM 4
#define NSTACKS 32
#define F_DIM 8192
#define KS 8                 // K splits
#define KSPAN (R_DIM / KS)   // 64
#define TR 64                // atoms per tile
#define TC 128               // cols per tile
#define KT 16                // k chunk
#define RT_TILES 11          // covers cnt_s up to 704 (mean 512, sd 19.4 — 9.9 sigma)
#define NTILES (8 * 2 * RT_TILES * S_DIM)  // 704 blocks; 3/CU x 256 CU = 768 >= 704 co-resident

// DPP lane-permute as a VALU op (validated R6/R7):
//   0xB1 quad_perm[1,0,3,2]=xor1 ; 0x4E quad_perm[2,3,0,1]=xor2 ;
//   0x128 row_ror:8=xor8 ; 0x124 row_ror:4 (sum-reduce only) ;
//   0x104 row_shl:4 (lane i <- i+4) ; 0x114 row_shr:4 (lane i <- i-4).
// NEVER put DPP calls inside conditional expressions — compute both, select.
#define DPPF(x, ctrl) \
  __int_as_float(__builtin_amdgcn_update_dpp( \
      __float_as_int(x), __float_as_int(x), (ctrl), 0xF, 0xF, false))

// ws layout: bar u32 @8192 (memset to 0 each launch) ; projp float[KS][2048][256] @16384

__global__ __launch_bounds__(256, 3) void sorf_one_kernel(
    const float* __restrict__ rep, const float* __restrict__ reductors,
    const int* __restrict__ charges, const float* __restrict__ Dmat,
    const float* __restrict__ bias, const float* __restrict__ alpha,
    float* __restrict__ projp, unsigned* __restrict__ bar,
    float* __restrict__ out) {
  __shared__ int rowsL[TR];
  __shared__ int wtot[4];
  __shared__ float As[KT][TR + 4];   // stride 68: 16B-aligned rows, 2-way aliasing (free)
  __shared__ float Bs[KT][TC];       // quads at tx*4 and 64+tx*4: 2-way (free)

  const int t = threadIdx.x;
  const int lane = t & 63;
  const int wave = t >> 6;
  const int bid = blockIdx.x;

  if (bid == 0 && t < 32) out[t] = 0.f;  // d_out poisoned each launch; fenced before barrier

  // ================= phase A: projection GEMM (one tile per block) =========
  {
    int ks = bid & 7;
    int cb = (bid >> 3) & 1;
    int r2 = bid >> 4;            // 0..43
    int rt = r2 % RT_TILES;
    int s  = r2 / RT_TILES;

    // ---- in-block charge scan: row list for this (s, rt) tile ----
    int4 c0v = ((const int4*)charges)[t * 2];
    int4 c1v = ((const int4*)charges)[t * 2 + 1];
    int fl[8];
    fl[0] = (c0v.x == s); fl[1] = (c0v.y == s); fl[2] = (c0v.z == s); fl[3] = (c0v.w == s);
    fl[4] = (c1v.x == s); fl[5] = (c1v.y == s); fl[6] = (c1v.z == s); fl[7] = (c1v.w == s);
    int cnt8 = ((fl[0] + fl[1]) + (fl[2] + fl[3])) + ((fl[4] + fl[5]) + (fl[6] + fl[7]));
    int scan = cnt8;                     // inclusive scan over lanes
#pragma unroll
    for (int o = 1; o < 64; o <<= 1) {
      int y = __shfl_up(scan, o);
      if (lane >= o) scan += y;
    }
    if (lane == 63) wtot[wave] = scan;
    __syncthreads();
    int wb = 0;
#pragma unroll
    for (int w = 0; w < 4; ++w) wb += (w < wave) ? wtot[w] : 0;
    int total = (wtot[0] + wtot[1]) + (wtot[2] + wtot[3]);
    int lo = rt * TR;
    int nrows = min(TR, total - lo);     // uniform across block
    if (nrows > 0) {                     // uniform branch; all barriers inside; no return
      if (t >= nrows && t < TR) rowsL[t] = 0;  // dummy rows (stores guarded)
      int pos = wb + scan - cnt8;        // exclusive prefix
#pragma unroll
      for (int i = 0; i < 8; ++i) {
        if (fl[i]) {
          int rel = pos - lo;
          if (rel >= 0 && rel < TR) rowsL[rel] = t * 8 + i;
          pos++;
        }
      }
      __syncthreads();

      // ---- 64 x 128 tile GEMM over this ks K-slice (4x8 register tile) ----
      int ar = t >> 2;        // A row staged by this thread
      int aq = t & 3;         // k-quad within KT chunk
      const float* aSrc = rep + (size_t)rowsL[ar] * R_DIM + ks * KSPAN + aq * 4;
      int kb = t >> 4;        // B k row
      int cc = (t & 15) * 4;  // B col quad (plus +64 partner)
      const float* bSrc = reductors + ((size_t)s * R_DIM + ks * KSPAN + kb) * P_DIM + cb * TC + cc;

      int ty = t >> 4, tx = t & 15;
      int r0 = ty * 4;
      int c0 = tx * 4;

      float acc[4][8];
#pragma unroll
      for (int i = 0; i < 4; ++i)
#pragma unroll
        for (int j = 0; j < 8; ++j) acc[i][j] = 0.f;

      float4 a  = *(const float4*)aSrc;
      float4 b0 = *(const float4*)bSrc;
      float4 b1 = *(const float4*)(bSrc + 64);

#pragma unroll 1
      for (int k0 = 0; k0 < KSPAN; k0 += KT) {
        __syncthreads();   // previous iteration's LDS reads complete
        As[aq * 4 + 0][ar] = a.x;
        As[aq * 4 + 1][ar] = a.y;
        As[aq * 4 + 2][ar] = a.z;
        As[aq * 4 + 3][ar] = a.w;
        *(float4*)&Bs[kb][cc] = b0;
        *(float4*)&Bs[kb][cc + 64] = b1;
        __syncthreads();
        if (k0 + KT < KSPAN) {   // prefetch next chunk; overlaps compute below
          a  = *(const float4*)(aSrc + k0 + KT);
          b0 = *(const float4*)(bSrc + (size_t)(k0 + KT) * P_DIM);
          b1 = *(const float4*)(bSrc + (size_t)(k0 + KT) * P_DIM + 64);
        }
#pragma unroll
        for (int kk = 0; kk < KT; ++kk) {
          float4 aV = *(const float4*)&As[kk][r0];
          float4 bA = *(const float4*)&Bs[kk][c0];
          float4 bB = *(const float4*)&Bs[kk][c0 + 64];
          float av[4] = {aV.x, aV.y, aV.z, aV.w};
          float bv[8] = {bA.x, bA.y, bA.z, bA.w, bB.x, bB.y, bB.z, bB.w};
#pragma unroll
          for (int i = 0; i < 4; ++i)
#pragma unroll
            for (int j = 0; j < 8; ++j) acc[i][j] = fmaf(av[i], bv[j], acc[i][j]);
        }
      }

      // coalesced: 16 threads (tx) cover each 256B half-row segment
#pragma unroll
      for (int i = 0; i < 4; ++i) {
        int r = r0 + i;
        if (r < nrows) {
          float* dst = projp + ((size_t)ks * NATOMS + rowsL[r]) * P_DIM + cb * TC + c0;
          *(float4*)dst = make_float4(acc[i][0], acc[i][1], acc[i][2], acc[i][3]);
          *(float4*)(dst + 64) = make_float4(acc[i][4], acc[i][5], acc[i][6], acc[i][7]);
        }
      }
    }
  }

  // ========== manual grid barrier (all 704 blocks co-resident) =============
  __threadfence();             // release: projp stores + out zeros visible device-wide
  __syncthreads();             // whole block done with phase A
  if (t == 0) {
    __hip_atomic_fetch_add(bar, 1u, __ATOMIC_RELEASE, __HIP_MEMORY_SCOPE_AGENT);
    while (__hip_atomic_load(bar, __ATOMIC_ACQUIRE, __HIP_MEMORY_SCOPE_AGENT) <
           (unsigned)gridDim.x) {
      __builtin_amdgcn_s_sleep(2);
    }
  }
  __syncthreads();             // rest of block waits for t0
  __threadfence();             // acquire side for all threads

  // ================= phase B: FWHT + cos + dot (one wave per atom) =========
  {
    int atom = bid * 4 + wave;           // 704*4 = 2816 waves; 2048 do work
    if (atom < NATOMS) {
      const int s = charges[atom];

      float4 p = *((const float4*)(projp + (size_t)atom * P_DIM) + lane);
#pragma unroll
      for (int ksi = 1; ksi < KS; ++ksi) {
        float4 q = *((const float4*)(projp + ((size_t)ksi * NATOMS + atom) * P_DIM) + lane);
        p.x += q.x; p.y += q.y; p.z += q.z; p.w += q.w;
      }

      const float sg1  = (lane & 1)  ? -1.f : 1.f;
      const float sg2  = (lane & 2)  ? -1.f : 1.f;
      const float sg4  = (lane & 4)  ? -1.f : 1.f;
      const float sg8  = (lane & 8)  ? -1.f : 1.f;
      const float sg16 = (lane & 16) ? -1.f : 1.f;
      const float sg32 = (lane & 32) ? -1.f : 1.f;
      const bool hi4 = (lane & 4) != 0;

      const float* Db = Dmat + (size_t)s * (NSTACKS * P_DIM);
      const float* bb = bias + (size_t)s * F_DIM;
      float accum = 0.f;

#pragma unroll 2
      for (int j = 0; j < NSTACKS; ++j) {
        float4 d  = *((const float4*)(Db + j * P_DIM) + lane);
        float4 bi = *((const float4*)(bb + j * P_DIM) + lane);
        float4 al = *((const float4*)(alpha + j * P_DIM) + lane);
        float x0 = (d.x >= 0.f) ? p.x : -p.x;
        float x1 = (d.y >= 0.f) ? p.y : -p.y;
        float x2 = (d.z >= 0.f) ? p.z : -p.z;
        float x3 = (d.w >= 0.f) ? p.w : -p.w;
        // FWHT bits 0,1 in-register
        float t0 = x0 + x1, t1 = x0 - x1, t2 = x2 + x3, t3 = x2 - x3;
        x0 = t0 + t2; x2 = t0 - t2; x1 = t1 + t3; x3 = t1 - t3;
        // xor1 (DPP)
        { float y0 = DPPF(x0, 0xB1), y1 = DPPF(x1, 0xB1), y2 = DPPF(x2, 0xB1), y3 = DPPF(x3, 0xB1);
          x0 = fmaf(sg1, x0, y0); x1 = fmaf(sg1, x1, y1);
          x2 = fmaf(sg1, x2, y2); x3 = fmaf(sg1, x3, y3); }
        // xor2 (DPP)
        { float y0 = DPPF(x0, 0x4E), y1 = DPPF(x1, 0x4E), y2 = DPPF(x2, 0x4E), y3 = DPPF(x3, 0x4E);
          x0 = fmaf(sg2, x0, y0); x1 = fmaf(sg2, x1, y1);
          x2 = fmaf(sg2, x2, y2); x3 = fmaf(sg2, x3, y3); }
        // xor4: both DPP shifts unconditionally, branchless select (validated R7)
        { float a0 = DPPF(x0, 0x104), a1 = DPPF(x1, 0x104), a2 = DPPF(x2, 0x104), a3 = DPPF(x3, 0x104);
          float b0 = DPPF(x0, 0x114), b1 = DPPF(x1, 0x114), b2 = DPPF(x2, 0x114), b3 = DPPF(x3, 0x114);
          float y0 = hi4 ? b0 : a0;
          float y1 = hi4 ? b1 : a1;
          float y2 = hi4 ? b2 : a2;
          float y3 = hi4 ? b3 : a3;
          x0 = fmaf(sg4, x0, y0); x1 = fmaf(sg4, x1, y1);
          x2 = fmaf(sg4, x2, y2); x3 = fmaf(sg4, x3, y3); }
        // xor8 (DPP row_ror:8)
        { float y0 = DPPF(x0, 0x128), y1 = DPPF(x1, 0x128), y2 = DPPF(x2, 0x128), y3 = DPPF(x3, 0x128);
          x0 = fmaf(sg8, x0, y0); x1 = fmaf(sg8, x1, y1);
          x2 = fmaf(sg8, x2, y2); x3 = fmaf(sg8, x3, y3); }
        // xor16 (shfl)
        { float y0 = __shfl_xor(x0, 16), y1 = __shfl_xor(x1, 16),
                y2 = __shfl_xor(x2, 16), y3 = __shfl_xor(x3, 16);
          x0 = fmaf(sg16, x0, y0); x1 = fmaf(sg16, x1, y1);
          x2 = fmaf(sg16, x2, y2); x3 = fmaf(sg16, x3, y3); }
        // xor32 (shfl)
        { float y0 = __shfl_xor(x0, 32), y1 = __shfl_xor(x1, 32),
                y2 = __shfl_xor(x2, 32), y3 = __shfl_xor(x3, 32);
          x0 = fmaf(sg32, x0, y0); x1 = fmaf(sg32, x1, y1);
          x2 = fmaf(sg32, x2, y2); x3 = fmaf(sg32, x3, y3); }
        // fwht norm 1/16; COEFF_NORM = 1.0 exactly
        accum += __cosf(fmaf(x0, 0.0625f, bi.x)) * al.x;
        accum += __cosf(fmaf(x1, 0.0625f, bi.y)) * al.y;
        accum += __cosf(fmaf(x2, 0.0625f, bi.z)) * al.z;
        accum += __cosf(fmaf(x3, 0.0625f, bi.w)) * al.w;
      }

      // wave sum-reduce (permutation-invariant)
      accum += DPPF(accum, 0xB1);
      accum += DPPF(accum, 0x4E);
      accum += DPPF(accum, 0x124);   // row_ror:4
      accum += DPPF(accum, 0x128);   // row_ror:8
      accum += __shfl_xor(accum, 16);
      accum += __shfl_xor(accum, 32);

      if (lane == 0) {
        // FEAT_NORM = 1/64 exactly
        atomicAdd(out + (atom >> 6), 0.015625f * accum);
      }
    }
  }
}

extern "C" void kernel_launch(void* const* d_in, const int* in_sizes, int n_in,
                              void* d_out, int out_size, void* d_ws, size_t ws_size,
                              hipStream_t stream) {
  const float* rep       = (const float*)d_in[0];
  const int*   charges   = (const int*)d_in[1];
  const float* reductors = (const float*)d_in[2];
  const float* Dmat      = (const float*)d_in[3];
  const float* bias      = (const float*)d_in[4];
  const float* alpha     = (const float*)d_in[5];
  float* out = (float*)d_out;

  unsigned* bar  = (unsigned*)((char*)d_ws + 8192);
  float*   projp = (float*)((char*)d_ws + 16384);

  hipMemsetAsync(bar, 0, 64, stream);  // robust barrier init (graph-capture safe, proven R1)
  sorf_one_kernel<<<NTILES, 256, 0, stream>>>(rep, reductors, charges, Dmat,
                                              bias, alpha, projp, bar, out);
}

// Round 10
// 121.607 us; speedup vs baseline: 2.6181x; 2.6181x over previous
//
#include <hip/hip_runtime.h>

#define NATOMS 2048
#define R_DIM 512
#define P_DIM 256
#define S_DIM 4
#define NSTACKS 32
#define F_DIM 8192
#define KS 8                 // K splits
#define KSPAN (R_DIM / KS)   // 64
#define TR 64                // atoms per tile
#define TC 128               // cols per tile
#define KT 16                // k chunk
#define RT_TILES 11          // covers cnt_s up to 704 (mean 512, sd 19.4)

// DPP lane-permute as a VALU op (validated R6/R7):
//   0xB1 quad_perm[1,0,3,2]=xor1 ; 0x4E quad_perm[2,3,0,1]=xor2 ;
//   0x128 row_ror:8=xor8 ; 0x124 row_ror:4 (sum-reduce only) ;
//   0x104 row_shl:4 (lane i <- i+4) ; 0x114 row_shr:4 (lane i <- i-4).
// NEVER put DPP calls inside conditional expressions — compute both, select.
// Grid-wide sync (cooperative OR manual spin barrier) is ~200us on this
// harness (R8/R9) — never fuse across the proj->feat dependency.
#define DPPF(x, ctrl) \
  __int_as_float(__builtin_amdgcn_update_dpp( \
      __float_as_int(x), __float_as_int(x), (ctrl), 0xF, 0xF, false))

// ws layout: [16384, +16MB) : projp float[KS][2048][256]

// grid: bid = ks(8) | cb(1) | (rt,s): 8*2*11*4 = 704 blocks, 128 threads.
// 8x8 register tile: 4 ds_read_b128 per 64 FMA (DS-pipe is proj's binding pipe).
__global__ __launch_bounds__(128, 3) void sorf_proj_kernel(
    const float* __restrict__ rep, const float* __restrict__ reductors,
    const int* __restrict__ charges, float* __restrict__ projp,
    float* __restrict__ out) {
  int bid = blockIdx.x;
  int ks = bid & 7;
  int cb = (bid >> 3) & 1;
  int r2 = bid >> 4;            // 0..43
  int rt = r2 % RT_TILES;
  int s  = r2 / RT_TILES;

  int t = threadIdx.x;          // 0..127
  int lane = t & 63, wave = t >> 6;
  if (bid == 0 && t < 32) out[t] = 0.f;  // d_out re-poisoned each launch

  __shared__ int rowsL[TR];
  __shared__ int wtot[2];
  __shared__ float As[KT][TR + 4];   // stride 68: writes 2-way, reads broadcast (free)
  __shared__ float Bs[KT][TC];       // reads at tx*4 / 64+tx*4: 2-way (free)

  // ---- in-block charge scan: thread t owns atoms 16t..16t+15 ----
  int4 cv0 = ((const int4*)charges)[t * 4 + 0];
  int4 cv1 = ((const int4*)charges)[t * 4 + 1];
  int4 cv2 = ((const int4*)charges)[t * 4 + 2];
  int4 cv3 = ((const int4*)charges)[t * 4 + 3];
  int fl[16];
  fl[0]  = (cv0.x == s); fl[1]  = (cv0.y == s); fl[2]  = (cv0.z == s); fl[3]  = (cv0.w == s);
  fl[4]  = (cv1.x == s); fl[5]  = (cv1.y == s); fl[6]  = (cv1.z == s); fl[7]  = (cv1.w == s);
  fl[8]  = (cv2.x == s); fl[9]  = (cv2.y == s); fl[10] = (cv2.z == s); fl[11] = (cv2.w == s);
  fl[12] = (cv3.x == s); fl[13] = (cv3.y == s); fl[14] = (cv3.z == s); fl[15] = (cv3.w == s);
  int cnt16 = 0;
#pragma unroll
  for (int i = 0; i < 16; ++i) cnt16 += fl[i];
  int scan = cnt16;                    // inclusive scan over lanes
#pragma unroll
  for (int o = 1; o < 64; o <<= 1) {
    int y = __shfl_up(scan, o);
    if (lane >= o) scan += y;
  }
  if (lane == 63) wtot[wave] = scan;
  __syncthreads();
  int wb = (wave == 1) ? wtot[0] : 0;
  int total = wtot[0] + wtot[1];
  int lo = rt * TR;
  int nrows = min(TR, total - lo);     // uniform across block
  if (nrows > 0) {                     // uniform branch; all barriers inside
    if (t >= nrows && t < TR) rowsL[t] = 0;  // dummy rows (stores guarded)
    int pos = wb + scan - cnt16;       // exclusive prefix
#pragma unroll
    for (int i = 0; i < 16; ++i) {
      if (fl[i]) {
        int rel = pos - lo;
        if (rel >= 0 && rel < TR) rowsL[rel] = t * 16 + i;
        pos++;
      }
    }
    __syncthreads();

    // ---- 64 x 128 tile GEMM over this ks K-slice (8x8 register tile) ----
    int ar = t >> 1;        // A row staged (0..63)
    int aq = t & 1;         // which k-half of the KT chunk (8 k each)
    const float* aSrc = rep + (size_t)rowsL[ar] * R_DIM + ks * KSPAN + aq * 8;
    int kb = t >> 5;        // B k row base (0..3); stages rows kb, kb+4, kb+8, kb+12
    int cc = (t & 31) * 4;  // B col quad
    const float* bSrc = reductors + ((size_t)s * R_DIM + ks * KSPAN + kb) * P_DIM + cb * TC + cc;

    int tx = t & 15, ty = t >> 4;      // ty 0..7
    int r0 = ty * 8;
    int c0 = tx * 4;                   // cols c0..c0+3 and c0+64..c0+67

    float acc[8][8];
#pragma unroll
    for (int i = 0; i < 8; ++i)
#pragma unroll
      for (int j = 0; j < 8; ++j) acc[i][j] = 0.f;

    float4 a0 = *(const float4*)aSrc;
    float4 a1 = *(const float4*)(aSrc + 4);
    float4 b0 = *(const float4*)bSrc;
    float4 b1 = *(const float4*)(bSrc + (size_t)4 * P_DIM);
    float4 b2 = *(const float4*)(bSrc + (size_t)8 * P_DIM);
    float4 b3 = *(const float4*)(bSrc + (size_t)12 * P_DIM);

#pragma unroll 1
    for (int k0 = 0; k0 < KSPAN; k0 += KT) {
      __syncthreads();   // previous iteration's LDS reads complete
      As[aq * 8 + 0][ar] = a0.x;
      As[aq * 8 + 1][ar] = a0.y;
      As[aq * 8 + 2][ar] = a0.z;
      As[aq * 8 + 3][ar] = a0.w;
      As[aq * 8 + 4][ar] = a1.x;
      As[aq * 8 + 5][ar] = a1.y;
      As[aq * 8 + 6][ar] = a1.z;
      As[aq * 8 + 7][ar] = a1.w;
      *(float4*)&Bs[kb][cc]      = b0;
      *(float4*)&Bs[kb + 4][cc]  = b1;
      *(float4*)&Bs[kb + 8][cc]  = b2;
      *(float4*)&Bs[kb + 12][cc] = b3;
      __syncthreads();
      if (k0 + KT < KSPAN) {   // prefetch next chunk; latency overlaps compute
        a0 = *(const float4*)(aSrc + k0 + KT);
        a1 = *(const float4*)(aSrc + k0 + KT + 4);
        const float* bp = bSrc + (size_t)(k0 + KT) * P_DIM;
        b0 = *(const float4*)bp;
        b1 = *(const float4*)(bp + (size_t)4 * P_DIM);
        b2 = *(const float4*)(bp + (size_t)8 * P_DIM);
        b3 = *(const float4*)(bp + (size_t)12 * P_DIM);
      }
#pragma unroll
      for (int kk = 0; kk < KT; ++kk) {
        float4 aA = *(const float4*)&As[kk][r0];
        float4 aB = *(const float4*)&As[kk][r0 + 4];
        float4 bA = *(const float4*)&Bs[kk][c0];
        float4 bB = *(const float4*)&Bs[kk][c0 + 64];
        float av[8] = {aA.x, aA.y, aA.z, aA.w, aB.x, aB.y, aB.z, aB.w};
        float bv[8] = {bA.x, bA.y, bA.z, bA.w, bB.x, bB.y, bB.z, bB.w};
#pragma unroll
        for (int i = 0; i < 8; ++i)
#pragma unroll
          for (int j = 0; j < 8; ++j) acc[i][j] = fmaf(av[i], bv[j], acc[i][j]);
      }
    }

    // coalesced: 16 threads (tx) cover each 256B half-row segment
#pragma unroll
    for (int i = 0; i < 8; ++i) {
      int r = r0 + i;
      if (r < nrows) {
        float* dst = projp + ((size_t)ks * NATOMS + rowsL[r]) * P_DIM + cb * TC + c0;
        *(float4*)dst = make_float4(acc[i][0], acc[i][1], acc[i][2], acc[i][3]);
        *(float4*)(dst + 64) = make_float4(acc[i][4], acc[i][5], acc[i][6], acc[i][7]);
      }
    }
  }
}

// grid: one block per atom; wave w handles stacks [w*8, w*8+8)
__global__ __launch_bounds__(256) void sorf_feat_kernel(
    const float* __restrict__ projp, const int* __restrict__ charges,
    const float* __restrict__ Dmat, const float* __restrict__ bias,
    const float* __restrict__ alpha, float* __restrict__ out) {
  const int atom = blockIdx.x;
  const int t = threadIdx.x;
  const int lane = t & 63;
  const int wave = t >> 6;
  const int s = charges[atom];

  // lane holds p = 4*lane+k; reduce the KS K-split partials in-register
  float4 p = *((const float4*)(projp + (size_t)atom * P_DIM) + lane);
#pragma unroll
  for (int ksi = 1; ksi < KS; ++ksi) {
    float4 q = *((const float4*)(projp + ((size_t)ksi * NATOMS + atom) * P_DIM) + lane);
    p.x += q.x; p.y += q.y; p.z += q.z; p.w += q.w;
  }

  const float sg1  = (lane & 1)  ? -1.f : 1.f;
  const float sg2  = (lane & 2)  ? -1.f : 1.f;
  const float sg4  = (lane & 4)  ? -1.f : 1.f;
  const float sg8  = (lane & 8)  ? -1.f : 1.f;
  const float sg16 = (lane & 16) ? -1.f : 1.f;
  const float sg32 = (lane & 32) ? -1.f : 1.f;
  const bool hi4 = (lane & 4) != 0;

  const float* Db = Dmat + (size_t)s * (NSTACKS * P_DIM);
  const float* bb = bias + (size_t)s * F_DIM;
  float accum = 0.f;

#pragma unroll 2
  for (int j = wave * 8; j < wave * 8 + 8; ++j) {
    float4 d  = *((const float4*)(Db + j * P_DIM) + lane);
    float4 bi = *((const float4*)(bb + j * P_DIM) + lane);
    float4 al = *((const float4*)(alpha + j * P_DIM) + lane);
    float x0 = (d.x >= 0.f) ? p.x : -p.x;
    float x1 = (d.y >= 0.f) ? p.y : -p.y;
    float x2 = (d.z >= 0.f) ? p.z : -p.z;
    float x3 = (d.w >= 0.f) ? p.w : -p.w;
    // FWHT bits 0,1 in-register
    float t0 = x0 + x1, t1 = x0 - x1, t2 = x2 + x3, t3 = x2 - x3;
    x0 = t0 + t2; x2 = t0 - t2; x1 = t1 + t3; x3 = t1 - t3;
    // xor1 (DPP)
    { float y0 = DPPF(x0, 0xB1), y1 = DPPF(x1, 0xB1), y2 = DPPF(x2, 0xB1), y3 = DPPF(x3, 0xB1);
      x0 = fmaf(sg1, x0, y0); x1 = fmaf(sg1, x1, y1);
      x2 = fmaf(sg1, x2, y2); x3 = fmaf(sg1, x3, y3); }
    // xor2 (DPP)
    { float y0 = DPPF(x0, 0x4E), y1 = DPPF(x1, 0x4E), y2 = DPPF(x2, 0x4E), y3 = DPPF(x3, 0x4E);
      x0 = fmaf(sg2, x0, y0); x1 = fmaf(sg2, x1, y1);
      x2 = fmaf(sg2, x2, y2); x3 = fmaf(sg2, x3, y3); }
    // xor4: both DPP shifts unconditionally, branchless select (validated R7)
    { float a0 = DPPF(x0, 0x104), a1 = DPPF(x1, 0x104), a2 = DPPF(x2, 0x104), a3 = DPPF(x3, 0x104);
      float b0 = DPPF(x0, 0x114), b1 = DPPF(x1, 0x114), b2 = DPPF(x2, 0x114), b3 = DPPF(x3, 0x114);
      float y0 = hi4 ? b0 : a0;
      float y1 = hi4 ? b1 : a1;
      float y2 = hi4 ? b2 : a2;
      float y3 = hi4 ? b3 : a3;
      x0 = fmaf(sg4, x0, y0); x1 = fmaf(sg4, x1, y1);
      x2 = fmaf(sg4, x2, y2); x3 = fmaf(sg4, x3, y3); }
    // xor8 (DPP row_ror:8)
    { float y0 = DPPF(x0, 0x128), y1 = DPPF(x1, 0x128), y2 = DPPF(x2, 0x128), y3 = DPPF(x3, 0x128);
      x0 = fmaf(sg8, x0, y0); x1 = fmaf(sg8, x1, y1);
      x2 = fmaf(sg8, x2, y2); x3 = fmaf(sg8, x3, y3); }
    // xor16 (shfl)
    { float y0 = __shfl_xor(x0, 16), y1 = __shfl_xor(x1, 16),
            y2 = __shfl_xor(x2, 16), y3 = __shfl_xor(x3, 16);
      x0 = fmaf(sg16, x0, y0); x1 = fmaf(sg16, x1, y1);
      x2 = fmaf(sg16, x2, y2); x3 = fmaf(sg16, x3, y3); }
    // xor32 (shfl)
    { float y0 = __shfl_xor(x0, 32), y1 = __shfl_xor(x1, 32),
            y2 = __shfl_xor(x2, 32), y3 = __shfl_xor(x3, 32);
      x0 = fmaf(sg32, x0, y0); x1 = fmaf(sg32, x1, y1);
      x2 = fmaf(sg32, x2, y2); x3 = fmaf(sg32, x3, y3); }
    // fwht norm 1/16; COEFF_NORM = 1.0 exactly
    accum += __cosf(fmaf(x0, 0.0625f, bi.x)) * al.x;
    accum += __cosf(fmaf(x1, 0.0625f, bi.y)) * al.y;
    accum += __cosf(fmaf(x2, 0.0625f, bi.z)) * al.z;
    accum += __cosf(fmaf(x3, 0.0625f, bi.w)) * al.w;
  }

  // wave sum-reduce (permutation-invariant)
  accum += DPPF(accum, 0xB1);
  accum += DPPF(accum, 0x4E);
  accum += DPPF(accum, 0x124);   // row_ror:4
  accum += DPPF(accum, 0x128);   // row_ror:8
  accum += __shfl_xor(accum, 16);
  accum += __shfl_xor(accum, 32);

  __shared__ float wsum[4];
  if (lane == 0) wsum[wave] = accum;
  __syncthreads();
  if (t == 0) {
    // FEAT_NORM = 1/64 exactly
    atomicAdd(out + (atom >> 6), 0.015625f * ((wsum[0] + wsum[1]) + (wsum[2] + wsum[3])));
  }
}

extern "C" void kernel_launch(void* const* d_in, const int* in_sizes, int n_in,
                              void* d_out, int out_size, void* d_ws, size_t ws_size,
                              hipStream_t stream) {
  const float* rep       = (const float*)d_in[0];
  const int*   charges   = (const int*)d_in[1];
  const float* reductors = (const float*)d_in[2];
  const float* Dmat      = (const float*)d_in[3];
  const float* bias      = (const float*)d_in[4];
  const float* alpha     = (const float*)d_in[5];
  float* out = (float*)d_out;

  float* projp = (float*)((char*)d_ws + 16384);

  sorf_proj_kernel<<<8 * 2 * RT_TILES * S_DIM, 128, 0, stream>>>(
      rep, reductors, charges, projp, out);
  sorf_feat_kernel<<<NATOMS, 256, 0, stream>>>(projp, charges, Dmat, bias, alpha, out);
}

// Round 11
// 110.338 us; speedup vs baseline: 2.8855x; 1.1021x over previous
//
#include <hip/hip_runtime.h>

#define NATOMS 2048
#define R_DIM 512
#define P_DIM 256
#define S_DIM 4
#define NSTACKS 32
#define F_DIM 8192
#define KS 8                 // K splits
#define KSPAN (R_DIM / KS)   // 64
#define TR 64                // atoms per tile
#define TC 128               // cols per tile
#define KT 16                // k chunk
#define RT_TILES 11          // covers cnt_s up to 704 (mean 512, sd 19.4 — 9.9 sigma)

// DPP lane-permute as a VALU op (validated R6/R7):
//   0xB1 quad_perm[1,0,3,2]=xor1 ; 0x4E quad_perm[2,3,0,1]=xor2 ;
//   0x128 row_ror:8=xor8 ; 0x124 row_ror:4 (sum-reduce only) ;
//   0x104 row_shl:4 (lane i <- i+4) ; 0x114 row_shr:4 (lane i <- i-4).
// NEVER put DPP calls inside conditional expressions — compute both, select.
// Session laws (measured): grid-wide sync (cooperative OR manual spin) costs
// ~200us here (R8/R9) — never fuse across proj->feat. 128-thread proj blocks
// (R10) drop to 1.5 waves/SIMD and lose ~10us to exposed staging latency.
#define DPPF(x, ctrl) \
  __int_as_float(__builtin_amdgcn_update_dpp( \
      __float_as_int(x), __float_as_int(x), (ctrl), 0xF, 0xF, false))

// ws layout: [16384, +16MB) : projp float[KS][2048][256]

// grid: bid = ks(8) | cb(1) | (rt,s): 8*2*11*4 = 704 blocks, 256 threads.
__global__ __launch_bounds__(256) void sorf_proj_kernel(
    const float* __restrict__ rep, const float* __restrict__ reductors,
    const int* __restrict__ charges, float* __restrict__ projp,
    float* __restrict__ out) {
  int bid = blockIdx.x;
  int ks = bid & 7;
  int cb = (bid >> 3) & 1;
  int r2 = bid >> 4;            // 0..43
  int rt = r2 % RT_TILES;
  int s  = r2 / RT_TILES;

  int t = threadIdx.x;
  int lane = t & 63, wave = t >> 6;
  if (bid == 0 && t < 32) out[t] = 0.f;  // d_out re-poisoned each launch

  // ---- in-block charge scan: row list for this (s, rt) tile ----
  // thread t owns atoms 8t..8t+7 (ascending thread order == atom order).
  __shared__ int rowsL[TR];
  __shared__ int wtot[4];
  int4 c0v = ((const int4*)charges)[t * 2];
  int4 c1v = ((const int4*)charges)[t * 2 + 1];
  int fl[8];
  fl[0] = (c0v.x == s); fl[1] = (c0v.y == s); fl[2] = (c0v.z == s); fl[3] = (c0v.w == s);
  fl[4] = (c1v.x == s); fl[5] = (c1v.y == s); fl[6] = (c1v.z == s); fl[7] = (c1v.w == s);
  int cnt8 = ((fl[0] + fl[1]) + (fl[2] + fl[3])) + ((fl[4] + fl[5]) + (fl[6] + fl[7]));
  int scan = cnt8;                       // inclusive scan over lanes
#pragma unroll
  for (int o = 1; o < 64; o <<= 1) {
    int y = __shfl_up(scan, o);
    if (lane >= o) scan += y;
  }
  if (lane == 63) wtot[wave] = scan;
  __syncthreads();
  int wb = 0;
#pragma unroll
  for (int w = 0; w < 4; ++w) wb += (w < wave) ? wtot[w] : 0;
  int total = (wtot[0] + wtot[1]) + (wtot[2] + wtot[3]);
  int lo = rt * TR;
  int nrows = min(TR, total - lo);       // uniform across block
  if (nrows <= 0) return;
  if (t >= nrows && t < TR) rowsL[t] = 0;  // dummy rows for staging reads (stores guarded)
  int pos = wb + scan - cnt8;            // exclusive prefix = rank of this thread's 1st match
#pragma unroll
  for (int i = 0; i < 8; ++i) {
    if (fl[i]) {
      int rel = pos - lo;
      if (rel >= 0 && rel < TR) rowsL[rel] = t * 8 + i;
      pos++;
    }
  }
  __syncthreads();

  // ---- 64 x 128 tile GEMM over this ks K-slice (4x8 register tile) ----
  __shared__ float As[KT][TR + 4];   // stride 68: 16B-aligned rows, 2-way aliasing (free)
  __shared__ float Bs[KT][TC];       // quads read at tx*4 and 64+tx*4: 2-way (free)

  int ar = t >> 2;        // A row staged by this thread
  int aq = t & 3;         // k-quad within KT chunk
  const float* aSrc = rep + (size_t)rowsL[ar] * R_DIM + ks * KSPAN + aq * 4;
  int kb = t >> 4;        // B k row
  int cc = (t & 15) * 4;  // B col quad (plus +64 partner)
  const float* bSrc = reductors + ((size_t)s * R_DIM + ks * KSPAN + kb) * P_DIM + cb * TC + cc;

  int ty = t >> 4, tx = t & 15;
  int r0 = ty * 4;
  int c0 = tx * 4;        // cols c0..c0+3 and c0+64..c0+67

  float acc[4][8];
#pragma unroll
  for (int i = 0; i < 4; ++i)
#pragma unroll
    for (int j = 0; j < 8; ++j) acc[i][j] = 0.f;

  float4 a  = *(const float4*)aSrc;
  float4 b0 = *(const float4*)bSrc;
  float4 b1 = *(const float4*)(bSrc + 64);

#pragma unroll 1
  for (int k0 = 0; k0 < KSPAN; k0 += KT) {
    __syncthreads();   // previous iteration's LDS reads complete
    As[aq * 4 + 0][ar] = a.x;
    As[aq * 4 + 1][ar] = a.y;
    As[aq * 4 + 2][ar] = a.z;
    As[aq * 4 + 3][ar] = a.w;
    *(float4*)&Bs[kb][cc] = b0;
    *(float4*)&Bs[kb][cc + 64] = b1;
    __syncthreads();
    if (k0 + KT < KSPAN) {   // prefetch next chunk; latency overlaps compute below
      a  = *(const float4*)(aSrc + k0 + KT);
      b0 = *(const float4*)(bSrc + (size_t)(k0 + KT) * P_DIM);
      b1 = *(const float4*)(bSrc + (size_t)(k0 + KT) * P_DIM + 64);
    }
#pragma unroll
    for (int kk = 0; kk < KT; ++kk) {
      float4 aV = *(const float4*)&As[kk][r0];
      float4 bA = *(const float4*)&Bs[kk][c0];
      float4 bB = *(const float4*)&Bs[kk][c0 + 64];
      float av[4] = {aV.x, aV.y, aV.z, aV.w};
      float bv[8] = {bA.x, bA.y, bA.z, bA.w, bB.x, bB.y, bB.z, bB.w};
#pragma unroll
      for (int i = 0; i < 4; ++i)
#pragma unroll
        for (int j = 0; j < 8; ++j) acc[i][j] = fmaf(av[i], bv[j], acc[i][j]);
    }
  }

  // coalesced: 16 threads (tx) cover each 256B half-row segment
#pragma unroll
  for (int i = 0; i < 4; ++i) {
    int r = r0 + i;
    if (r < nrows) {
      float* dst = projp + ((size_t)ks * NATOMS + rowsL[r]) * P_DIM + cb * TC + c0;
      *(float4*)dst = make_float4(acc[i][0], acc[i][1], acc[i][2], acc[i][3]);
      *(float4*)(dst + 64) = make_float4(acc[i][4], acc[i][5], acc[i][6], acc[i][7]);
    }
  }
}

// grid: one block per atom; wave w handles stacks [w*8, w*8+8)
__global__ __launch_bounds__(256) void sorf_feat_kernel(
    const float* __restrict__ projp, const int* __restrict__ charges,
    const float* __restrict__ Dmat, const float* __restrict__ bias,
    const float* __restrict__ alpha, float* __restrict__ out) {
  const int atom = blockIdx.x;
  const int t = threadIdx.x;
  const int lane = t & 63;
  const int wave = t >> 6;
  const int s = charges[atom];

  // lane holds p = 4*lane+k; reduce the KS K-split partials in-register
  float4 p = *((const float4*)(projp + (size_t)atom * P_DIM) + lane);
#pragma unroll
  for (int ksi = 1; ksi < KS; ++ksi) {
    float4 q = *((const float4*)(projp + ((size_t)ksi * NATOMS + atom) * P_DIM) + lane);
    p.x += q.x; p.y += q.y; p.z += q.z; p.w += q.w;
  }

  const float sg1  = (lane & 1)  ? -1.f : 1.f;
  const float sg2  = (lane & 2)  ? -1.f : 1.f;
  const float sg4  = (lane & 4)  ? -1.f : 1.f;
  const float sg8  = (lane & 8)  ? -1.f : 1.f;
  const float sg16 = (lane & 16) ? -1.f : 1.f;
  const float sg32 = (lane & 32) ? -1.f : 1.f;
  const bool hi4 = (lane & 4) != 0;

  const float* Db = Dmat + (size_t)s * (NSTACKS * P_DIM);
  const float* bb = bias + (size_t)s * F_DIM;
  float accum = 0.f;

#pragma unroll 2
  for (int j = wave * 8; j < wave * 8 + 8; ++j) {
    float4 d  = *((const float4*)(Db + j * P_DIM) + lane);
    float4 bi = *((const float4*)(bb + j * P_DIM) + lane);
    float4 al = *((const float4*)(alpha + j * P_DIM) + lane);
    float x0 = (d.x >= 0.f) ? p.x : -p.x;
    float x1 = (d.y >= 0.f) ? p.y : -p.y;
    float x2 = (d.z >= 0.f) ? p.z : -p.z;
    float x3 = (d.w >= 0.f) ? p.w : -p.w;
    // FWHT bits 0,1 in-register
    float t0 = x0 + x1, t1 = x0 - x1, t2 = x2 + x3, t3 = x2 - x3;
    x0 = t0 + t2; x2 = t0 - t2; x1 = t1 + t3; x3 = t1 - t3;
    // xor1 (DPP)
    { float y0 = DPPF(x0, 0xB1), y1 = DPPF(x1, 0xB1), y2 = DPPF(x2, 0xB1), y3 = DPPF(x3, 0xB1);
      x0 = fmaf(sg1, x0, y0); x1 = fmaf(sg1, x1, y1);
      x2 = fmaf(sg1, x2, y2); x3 = fmaf(sg1, x3, y3); }
    // xor2 (DPP)
    { float y0 = DPPF(x0, 0x4E), y1 = DPPF(x1, 0x4E), y2 = DPPF(x2, 0x4E), y3 = DPPF(x3, 0x4E);
      x0 = fmaf(sg2, x0, y0); x1 = fmaf(sg2, x1, y1);
      x2 = fmaf(sg2, x2, y2); x3 = fmaf(sg2, x3, y3); }
    // xor4: both DPP shifts unconditionally, branchless select (validated R7)
    { float a0 = DPPF(x0, 0x104), a1 = DPPF(x1, 0x104), a2 = DPPF(x2, 0x104), a3 = DPPF(x3, 0x104);
      float b0 = DPPF(x0, 0x114), b1 = DPPF(x1, 0x114), b2 = DPPF(x2, 0x114), b3 = DPPF(x3, 0x114);
      float y0 = hi4 ? b0 : a0;
      float y1 = hi4 ? b1 : a1;
      float y2 = hi4 ? b2 : a2;
      float y3 = hi4 ? b3 : a3;
      x0 = fmaf(sg4, x0, y0); x1 = fmaf(sg4, x1, y1);
      x2 = fmaf(sg4, x2, y2); x3 = fmaf(sg4, x3, y3); }
    // xor8 (DPP row_ror:8)
    { float y0 = DPPF(x0, 0x128), y1 = DPPF(x1, 0x128), y2 = DPPF(x2, 0x128), y3 = DPPF(x3, 0x128);
      x0 = fmaf(sg8, x0, y0); x1 = fmaf(sg8, x1, y1);
      x2 = fmaf(sg8, x2, y2); x3 = fmaf(sg8, x3, y3); }
    // xor16 (shfl)
    { float y0 = __shfl_xor(x0, 16), y1 = __shfl_xor(x1, 16),
            y2 = __shfl_xor(x2, 16), y3 = __shfl_xor(x3, 16);
      x0 = fmaf(sg16, x0, y0); x1 = fmaf(sg16, x1, y1);
      x2 = fmaf(sg16, x2, y2); x3 = fmaf(sg16, x3, y3); }
    // xor32 (shfl)
    { float y0 = __shfl_xor(x0, 32), y1 = __shfl_xor(x1, 32),
            y2 = __shfl_xor(x2, 32), y3 = __shfl_xor(x3, 32);
      x0 = fmaf(sg32, x0, y0); x1 = fmaf(sg32, x1, y1);
      x2 = fmaf(sg32, x2, y2); x3 = fmaf(sg32, x3, y3); }
    // fwht norm 1/16; COEFF_NORM = 1.0 exactly
    accum += __cosf(fmaf(x0, 0.0625f, bi.x)) * al.x;
    accum += __cosf(fmaf(x1, 0.0625f, bi.y)) * al.y;
    accum += __cosf(fmaf(x2, 0.0625f, bi.z)) * al.z;
    accum += __cosf(fmaf(x3, 0.0625f, bi.w)) * al.w;
  }

  // wave sum-reduce (permutation-invariant)
  accum += DPPF(accum, 0xB1);
  accum += DPPF(accum, 0x4E);
  accum += DPPF(accum, 0x124);   // row_ror:4
  accum += DPPF(accum, 0x128);   // row_ror:8
  accum += __shfl_xor(accum, 16);
  accum += __shfl_xor(accum, 32);

  __shared__ float wsum[4];
  if (lane == 0) wsum[wave] = accum;
  __syncthreads();
  if (t == 0) {
    // FEAT_NORM = 1/64 exactly
    atomicAdd(out + (atom >> 6), 0.015625f * ((wsum[0] + wsum[1]) + (wsum[2] + wsum[3])));
  }
}

extern "C" void kernel_launch(void* const* d_in, const int* in_sizes, int n_in,
                              void* d_out, int out_size, void* d_ws, size_t ws_size,
                              hipStream_t stream) {
  const float* rep       = (const float*)d_in[0];
  const int*   charges   = (const int*)d_in[1];
  const float* reductors = (const float*)d_in[2];
  const float* Dmat      = (const float*)d_in[3];
  const float* bias      = (const float*)d_in[4];
  const float* alpha     = (const float*)d_in[5];
  float* out = (float*)d_out;

  float* projp = (float*)((char*)d_ws + 16384);

  sorf_proj_kernel<<<8 * 2 * RT_TILES * S_DIM, 256, 0, stream>>>(
      rep, reductors, charges, projp, out);
  sorf_feat_kernel<<<NATOMS, 256, 0, stream>>>(projp, charges, Dmat, bias, alpha, out);
}